// Round 1
// baseline (264.375 us; speedup 1.0000x reference)
//
#include <hip/hip_runtime.h>
#include <math.h>

namespace {
constexpr int H  = 8;
constexpr int B  = 4;
constexpr int S  = 1024;
constexpr int M  = 512;
constexpr int D  = 64;
constexpr int BS = B * S;            // 4096 rows
constexpr int NC = 16;               // chunks per sequence
constexpr int CH = 64;               // chunk length
constexpr int QSZ = H * B * S * D;   // 2097152 floats per tensor

__device__ __forceinline__ float elu1(float x) {
  // jax.nn.elu(x) + 1 = x>0 ? x+1 : exp(x)
  return x > 0.f ? x + 1.f : __expf(x);
}

// ---------------------------------------------------------------------------
// Kernel 1: q/k/v projections.  grid=(BS/64, 24) where y = p*8 + h.
// 64x64 output tile per block, 128 threads, 8 rows x 4 cols per thread.
// q,k get elu+1; v raw. Output layout [h][b][s][d].
// ---------------------------------------------------------------------------
__global__ __launch_bounds__(128) void proj_kernel(
    const float* __restrict__ X, const float* __restrict__ Wq,
    const float* __restrict__ Wk, const float* __restrict__ Wv,
    float* __restrict__ qkv_ws) {
  __shared__ float XT[64 * 64];   // [row][m]
  __shared__ float WT[64 * 64];   // [m][col]
  const int tid = threadIdx.x;
  const int p = blockIdx.y >> 3;      // 0:q 1:k 2:v
  const int h = blockIdx.y & 7;
  const float* W = (p == 0) ? Wq : (p == 1) ? Wk : Wv;
  W += h * (M * D);
  const int r0 = blockIdx.x * 64;
  const int c4 = tid & 15;            // 4-col group
  const int rg = tid >> 4;            // 8-row group (0..7)

  float acc[8][4];
#pragma unroll
  for (int i = 0; i < 8; ++i)
#pragma unroll
    for (int j = 0; j < 4; ++j) acc[i][j] = 0.f;

  for (int m0 = 0; m0 < M; m0 += 64) {
    __syncthreads();
#pragma unroll
    for (int i = tid; i < 4096; i += 128) {
      const int rr = i >> 6, mm = i & 63;
      XT[i] = X[(r0 + rr) * M + m0 + mm];       // XT[rr][mm]
      WT[i] = W[(m0 + rr) * D + mm];            // WT[m][c]
    }
    __syncthreads();
#pragma unroll
    for (int mm4 = 0; mm4 < 16; ++mm4) {
      float xr[8][4];
#pragma unroll
      for (int i = 0; i < 8; ++i) {
        const float4 t =
            reinterpret_cast<const float4*>(XT)[(rg * 8 + i) * 16 + mm4];
        xr[i][0] = t.x; xr[i][1] = t.y; xr[i][2] = t.z; xr[i][3] = t.w;
      }
#pragma unroll
      for (int j = 0; j < 4; ++j) {
        const float4 w =
            reinterpret_cast<const float4*>(WT)[(mm4 * 4 + j) * 16 + c4];
#pragma unroll
        for (int i = 0; i < 8; ++i) {
          acc[i][0] += xr[i][j] * w.x;
          acc[i][1] += xr[i][j] * w.y;
          acc[i][2] += xr[i][j] * w.z;
          acc[i][3] += xr[i][j] * w.w;
        }
      }
    }
  }

  float* dst = qkv_ws + p * QSZ;
#pragma unroll
  for (int i = 0; i < 8; ++i) {
    const int r = r0 + rg * 8 + i;
    const int b = r >> 10, s = r & 1023;
    float4 v;
    v.x = acc[i][0]; v.y = acc[i][1]; v.z = acc[i][2]; v.w = acc[i][3];
    if (p < 2) { v.x = elu1(v.x); v.y = elu1(v.y); v.z = elu1(v.z); v.w = elu1(v.w); }
    *reinterpret_cast<float4*>(dst + ((h * B + b) * S + s) * D + c4 * 4) = v;
  }
}

// ---------------------------------------------------------------------------
// Kernel 2: per-chunk Gram state G_c = sum_{t in chunk} k_t (x) v_t  [64x64]
// and per-chunk ksum.  grid = H*B*NC = 512 blocks, 256 threads.
// Thread (e = tid&63, dg = tid>>6) owns G[d0..d0+15][e].
// ---------------------------------------------------------------------------
__global__ __launch_bounds__(256) void chunkstate_kernel(
    const float* __restrict__ kws, const float* __restrict__ vws,
    float* __restrict__ G, float* __restrict__ Ks) {
  __shared__ float kT[4096], vT[4096];
  const int tid = threadIdx.x;
  const int bx = blockIdx.x;            // hb*NC + c
  const int hb = bx >> 4, cc = bx & 15;
  const float* kp = kws + (hb * S + cc * CH) * D;
  const float* vp = vws + (hb * S + cc * CH) * D;
  for (int i = tid; i < 4096; i += 256) { kT[i] = kp[i]; vT[i] = vp[i]; }
  __syncthreads();

  const int e = tid & 63, dg = tid >> 6, d0 = dg * 16;
  float g[16];
#pragma unroll
  for (int j = 0; j < 16; ++j) g[j] = 0.f;

  for (int t = 0; t < CH; ++t) {
    const float vv = vT[t * 64 + e];
#pragma unroll
    for (int jj = 0; jj < 4; ++jj) {
      const float4 kk =
          reinterpret_cast<const float4*>(kT)[t * 16 + (d0 >> 2) + jj];
      g[jj * 4 + 0] += kk.x * vv;
      g[jj * 4 + 1] += kk.y * vv;
      g[jj * 4 + 2] += kk.z * vv;
      g[jj * 4 + 3] += kk.w * vv;
    }
  }
  float* Gp = G + bx * 4096;
#pragma unroll
  for (int j = 0; j < 16; ++j) Gp[(d0 + j) * 64 + e] = g[j];
  if (dg == 0) {
    float ks = 0.f;
    for (int t = 0; t < CH; ++t) ks += kT[t * 64 + e];
    Ks[bx * 64 + e] = ks;
  }
}

// ---------------------------------------------------------------------------
// Kernel 3: exclusive prefix over chunks (in place).  grid = 32 (h*B+b).
// ---------------------------------------------------------------------------
__global__ __launch_bounds__(256) void prefix_kernel(float* __restrict__ G,
                                                     float* __restrict__ Ks) {
  const int tid = threadIdx.x, hb = blockIdx.x;
  const int e = tid & 63, dg = tid >> 6, d0 = dg * 16;
  float acc[16];
#pragma unroll
  for (int j = 0; j < 16; ++j) acc[j] = 0.f;
  for (int c = 0; c < NC; ++c) {
    float* Gp = G + (hb * NC + c) * 4096;
#pragma unroll
    for (int j = 0; j < 16; ++j) {
      const float t = Gp[(d0 + j) * 64 + e];
      Gp[(d0 + j) * 64 + e] = acc[j];
      acc[j] += t;
    }
  }
  if (dg == 0) {
    float ka = 0.f;
    for (int c = 0; c < NC; ++c) {
      const float t = Ks[(hb * NC + c) * 64 + e];
      Ks[(hb * NC + c) * 64 + e] = ka;
      ka += t;
    }
  }
}

// ---------------------------------------------------------------------------
// Kernel 4: per-chunk recurrence + normalize, writes combined att[b][s][h*64+e].
// grid = H*B*NC = 512 blocks, 256 threads; 64 sequential steps per block.
// ---------------------------------------------------------------------------
__global__ __launch_bounds__(256) void chunkout_kernel(
    const float* __restrict__ qws, const float* __restrict__ kws,
    const float* __restrict__ vws, const float* __restrict__ G,
    const float* __restrict__ Ks, float* __restrict__ att) {
  __shared__ float qT[4096], kT[4096], vT[4096];
  __shared__ float red[4 * 64];
  const int tid = threadIdx.x;
  const int bx = blockIdx.x;
  const int hb = bx >> 4, cc = bx & 15;
  const int h = hb >> 2, b = hb & 3;
  const int s0 = cc * CH;
  const float* qp = qws + (hb * S + s0) * D;
  const float* kp = kws + (hb * S + s0) * D;
  const float* vp = vws + (hb * S + s0) * D;
  for (int i = tid; i < 4096; i += 256) {
    qT[i] = qp[i]; kT[i] = kp[i]; vT[i] = vp[i];
  }
  const int e = tid & 63, dg = tid >> 6, d0 = dg * 16;
  float Sacc[16];
  const float* Gp = G + bx * 4096;
#pragma unroll
  for (int j = 0; j < 16; ++j) Sacc[j] = Gp[(d0 + j) * 64 + e];
  float kc = 0.f;
  if (tid < 64) kc = Ks[bx * 64 + tid];   // exclusive prefix of k-cumsum
  __syncthreads();

  float* attp = att + (b * S + s0) * M + h * D;
  for (int t = 0; t < CH; ++t) {
    // inclusive state update, then q.S partial over this thread's 16 d's
    const float vv = vT[t * 64 + e];
    float p = 0.f;
#pragma unroll
    for (int jj = 0; jj < 4; ++jj) {
      const float4 kk =
          reinterpret_cast<const float4*>(kT)[t * 16 + (d0 >> 2) + jj];
      const float4 qq =
          reinterpret_cast<const float4*>(qT)[t * 16 + (d0 >> 2) + jj];
      Sacc[jj * 4 + 0] += kk.x * vv;
      Sacc[jj * 4 + 1] += kk.y * vv;
      Sacc[jj * 4 + 2] += kk.z * vv;
      Sacc[jj * 4 + 3] += kk.w * vv;
      p += qq.x * Sacc[jj * 4 + 0] + qq.y * Sacc[jj * 4 + 1] +
           qq.z * Sacc[jj * 4 + 2] + qq.w * Sacc[jj * 4 + 3];
    }
    red[dg * 64 + e] = p;
    __syncthreads();
    if (tid < 64) {
      const float vb = red[e] + red[64 + e] + red[128 + e] + red[192 + e];
      kc += kT[t * 64 + tid];                       // inclusive k-cumsum[d]
      float zp = qT[t * 64 + tid] * kc;             // partial Z
#pragma unroll
      for (int off = 32; off >= 1; off >>= 1) zp += __shfl_xor(zp, off);
      attp[t * M + e] = vb / zp;
    }
    __syncthreads();
  }
}

// ---------------------------------------------------------------------------
// Kernel 5: output projection  out = att[4096,512] x Wo[512,512].
// Same tiling as proj_kernel; grid=(BS/64, M/64).
// ---------------------------------------------------------------------------
__global__ __launch_bounds__(128) void outproj_kernel(
    const float* __restrict__ att, const float* __restrict__ Wo,
    float* __restrict__ out) {
  __shared__ float XT[64 * 64];
  __shared__ float WT[64 * 64];
  const int tid = threadIdx.x;
  const int r0 = blockIdx.x * 64;
  const int c0 = blockIdx.y * 64;
  const int c4 = tid & 15;
  const int rg = tid >> 4;

  float acc[8][4];
#pragma unroll
  for (int i = 0; i < 8; ++i)
#pragma unroll
    for (int j = 0; j < 4; ++j) acc[i][j] = 0.f;

  for (int m0 = 0; m0 < M; m0 += 64) {
    __syncthreads();
#pragma unroll
    for (int i = tid; i < 4096; i += 128) {
      const int rr = i >> 6, mm = i & 63;
      XT[i] = att[(r0 + rr) * M + m0 + mm];
      WT[i] = Wo[(m0 + rr) * M + c0 + mm];
    }
    __syncthreads();
#pragma unroll
    for (int mm4 = 0; mm4 < 16; ++mm4) {
      float xr[8][4];
#pragma unroll
      for (int i = 0; i < 8; ++i) {
        const float4 t =
            reinterpret_cast<const float4*>(XT)[(rg * 8 + i) * 16 + mm4];
        xr[i][0] = t.x; xr[i][1] = t.y; xr[i][2] = t.z; xr[i][3] = t.w;
      }
#pragma unroll
      for (int j = 0; j < 4; ++j) {
        const float4 w =
            reinterpret_cast<const float4*>(WT)[(mm4 * 4 + j) * 16 + c4];
#pragma unroll
        for (int i = 0; i < 8; ++i) {
          acc[i][0] += xr[i][j] * w.x;
          acc[i][1] += xr[i][j] * w.y;
          acc[i][2] += xr[i][j] * w.z;
          acc[i][3] += xr[i][j] * w.w;
        }
      }
    }
  }
#pragma unroll
  for (int i = 0; i < 8; ++i) {
    const int r = r0 + rg * 8 + i;
    float4 v;
    v.x = acc[i][0]; v.y = acc[i][1]; v.z = acc[i][2]; v.w = acc[i][3];
    *reinterpret_cast<float4*>(out + r * M + c0 + c4 * 4) = v;
  }
}

}  // namespace

extern "C" void kernel_launch(void* const* d_in, const int* in_sizes, int n_in,
                              void* d_out, int out_size, void* d_ws,
                              size_t ws_size, hipStream_t stream) {
  const float* X  = (const float*)d_in[0];
  // d_in[1] = mask (unused by the module)
  const float* Wq = (const float*)d_in[2];
  const float* Wk = (const float*)d_in[3];
  const float* Wv = (const float*)d_in[4];
  const float* Wo = (const float*)d_in[5];
  float* out = (float*)d_out;

  float* ws  = (float*)d_ws;
  float* qkv = ws;              // q | k | v, each QSZ floats, [h][b][s][d]
  float* att = ws + 3 * (size_t)QSZ;   // combined [b][s][h*64+e]
  float* G   = ws + 4 * (size_t)QSZ;   // chunk states [hb][c][d][e]
  float* Ks  = ws + 5 * (size_t)QSZ;   // chunk ksums  [hb][c][d]

  proj_kernel<<<dim3(BS / 64, 24), 128, 0, stream>>>(X, Wq, Wk, Wv, qkv);
  chunkstate_kernel<<<dim3(H * B * NC), 256, 0, stream>>>(qkv + QSZ,
                                                          qkv + 2 * QSZ, G, Ks);
  prefix_kernel<<<dim3(H * B), 256, 0, stream>>>(G, Ks);
  chunkout_kernel<<<dim3(H * B * NC), 256, 0, stream>>>(
      qkv, qkv + QSZ, qkv + 2 * QSZ, G, Ks, att);
  outproj_kernel<<<dim3(BS / 64, M / 64), 128, 0, stream>>>(att, Wo, out);
}

// Round 2
// 99.401 us; speedup vs baseline: 2.6597x; 2.6597x over previous
//
#include <hip/hip_runtime.h>
#include <math.h>

namespace {
typedef unsigned short u16;
typedef __attribute__((ext_vector_type(8))) short bf16x8;
typedef __attribute__((ext_vector_type(4))) float f32x4;

constexpr int H  = 8;
constexpr int B  = 4;
constexpr int S  = 1024;
constexpr int M  = 512;
constexpr int D  = 64;
constexpr int BS = B * S;            // 4096 rows
constexpr int NC = 16;               // chunks per sequence
constexpr int CH = 64;               // chunk length
constexpr int QSZ = H * B * S * D;   // 2097152 elements per q/k/v tensor
constexpr int NQKV = 3 * M;          // 1536 combined qkv output cols

__device__ __forceinline__ float elu1(float x) {
  return x > 0.f ? x + 1.f : __expf(x);
}

__device__ __forceinline__ u16 f2bf(float f) {
  unsigned u = __builtin_bit_cast(unsigned, f);
  u += 0x7fffu + ((u >> 16) & 1u);   // RNE
  return (u16)(u >> 16);
}

__device__ __forceinline__ void gload16(const u16* g, u16* l) {
  __builtin_amdgcn_global_load_lds(
      (const __attribute__((address_space(1))) unsigned int*)g,
      (__attribute__((address_space(3))) unsigned int*)l, 16, 0, 0);
}

// ---------------------------------------------------------------------------
// X [4096,512] fp32 -> bf16
// ---------------------------------------------------------------------------
__global__ __launch_bounds__(256) void convert_x(const float* __restrict__ X,
                                                 u16* __restrict__ Xb) {
  const int i = blockIdx.x * 256 + threadIdx.x;   // float4 index
  const float4 v = reinterpret_cast<const float4*>(X)[i];
  u16 o[4] = {f2bf(v.x), f2bf(v.y), f2bf(v.z), f2bf(v.w)};
  *reinterpret_cast<uint2*>(Xb + i * 4) = *reinterpret_cast<uint2*>(o);
}

// ---------------------------------------------------------------------------
// Build WCT[1536][512] bf16 (row = p*512+h*64+d, k-contiguous) from
// Wq/Wk/Wv [8][512][64] fp32.  grid (8 m-tiles, 24 ph), 256 threads.
// ---------------------------------------------------------------------------
__global__ __launch_bounds__(256) void build_wqkv(
    const float* __restrict__ Wq, const float* __restrict__ Wk,
    const float* __restrict__ Wv, u16* __restrict__ WCT) {
  __shared__ float t[64][65];
  const int p = blockIdx.y >> 3, h = blockIdx.y & 7;
  const float* W = ((p == 0) ? Wq : (p == 1) ? Wk : Wv) + h * (M * D);
  const int m0 = blockIdx.x * 64;
#pragma unroll
  for (int j = 0; j < 4; ++j) {
    const int i = j * 256 + threadIdx.x;       // float4 idx in 64x64 tile
    const int mm = i >> 4, dd = (i & 15) * 4;
    const float4 v = *reinterpret_cast<const float4*>(W + (m0 + mm) * D + dd);
    t[mm][dd + 0] = v.x; t[mm][dd + 1] = v.y;
    t[mm][dd + 2] = v.z; t[mm][dd + 3] = v.w;
  }
  __syncthreads();
  const int dd = threadIdx.x >> 2, qr = (threadIdx.x & 3) * 16;
  u16* o = WCT + (p * M + h * D + dd) * M + m0 + qr;
#pragma unroll
  for (int i = 0; i < 16; ++i) o[i] = f2bf(t[qr + i][dd]);
}

// ---------------------------------------------------------------------------
// Build WoT[512][512] bf16 = Wo^T.  grid (8 m-tiles, 8 n-tiles).
// ---------------------------------------------------------------------------
__global__ __launch_bounds__(256) void build_wo(const float* __restrict__ Wo,
                                                u16* __restrict__ WoT) {
  __shared__ float t[64][65];
  const int m0 = blockIdx.x * 64, n0 = blockIdx.y * 64;
#pragma unroll
  for (int j = 0; j < 4; ++j) {
    const int i = j * 256 + threadIdx.x;
    const int mm = i >> 4, nn = (i & 15) * 4;
    const float4 v = *reinterpret_cast<const float4*>(Wo + (m0 + mm) * M + n0 + nn);
    t[mm][nn + 0] = v.x; t[mm][nn + 1] = v.y;
    t[mm][nn + 2] = v.z; t[mm][nn + 3] = v.w;
  }
  __syncthreads();
  const int nn = threadIdx.x >> 2, qr = (threadIdx.x & 3) * 16;
  u16* o = WoT + (n0 + nn) * M + m0 + qr;
#pragma unroll
  for (int i = 0; i < 16; ++i) o[i] = f2bf(t[qr + i][nn]);
}

// ---------------------------------------------------------------------------
// bf16 MFMA GEMM, 128x128 tile, BK=32, 256 threads (4 waves, 2x2 of 64x64).
// A [4096][512] bf16 row-major; BT [ncols][512] bf16 (row = out col).
// EPI 0: scatter to qkv [p][h][b][s][d] fp32 with elu on p<2.
// EPI 1: plain fp32 store out[row*512+col].
// ---------------------------------------------------------------------------
template <int EPI>
__global__ __launch_bounds__(256) void gemm_bf16(const u16* __restrict__ A,
                                                 const u16* __restrict__ BT,
                                                 float* __restrict__ out) {
  __shared__ alignas(16) u16 As[128 * 32];
  __shared__ alignas(16) u16 Bs[128 * 32];
  const int tid = threadIdx.x;
  const int wave = tid >> 6, lane = tid & 63;
  const int r0 = blockIdx.x * 128, c0 = blockIdx.y * 128;
  const int wr = (wave >> 1) * 64, wc = (wave & 1) * 64;

  f32x4 acc[4][4] = {};

  const int lrow = tid >> 2;              // 0..63
  const int lk = (tid & 3) * 8;
  const u16* ga0 = A + (size_t)(r0 + lrow) * 512 + lk;
  const u16* ga1 = A + (size_t)(r0 + 64 + lrow) * 512 + lk;
  const u16* gb0 = BT + (size_t)(c0 + lrow) * 512 + lk;
  const u16* gb1 = BT + (size_t)(c0 + 64 + lrow) * 512 + lk;
  u16* lA0 = &As[wave * 512];
  u16* lA1 = &As[2048 + wave * 512];
  u16* lB0 = &Bs[wave * 512];
  u16* lB1 = &Bs[2048 + wave * 512];

  for (int kt = 0; kt < 16; ++kt) {
    __syncthreads();
    const int ko = kt * 32;
    gload16(ga0 + ko, lA0);
    gload16(ga1 + ko, lA1);
    gload16(gb0 + ko, lB0);
    gload16(gb1 + ko, lB1);
    __syncthreads();
    const bf16x8* As8 = reinterpret_cast<const bf16x8*>(As);
    const bf16x8* Bs8 = reinterpret_cast<const bf16x8*>(Bs);
    bf16x8 af[4], bff[4];
#pragma unroll
    for (int mf = 0; mf < 4; ++mf)
      af[mf] = As8[(wr + mf * 16 + (lane & 15)) * 4 + (lane >> 4)];
#pragma unroll
    for (int nf = 0; nf < 4; ++nf)
      bff[nf] = Bs8[(wc + nf * 16 + (lane & 15)) * 4 + (lane >> 4)];
#pragma unroll
    for (int mf = 0; mf < 4; ++mf)
#pragma unroll
      for (int nf = 0; nf < 4; ++nf)
        acc[mf][nf] = __builtin_amdgcn_mfma_f32_16x16x32_bf16(
            af[mf], bff[nf], acc[mf][nf], 0, 0, 0);
  }

#pragma unroll
  for (int nf = 0; nf < 4; ++nf) {
    const int col = c0 + wc + nf * 16 + (lane & 15);
    if (EPI == 0) {
      const int p = col >> 9, hh = (col >> 6) & 7, d = col & 63;
      float* dst = out + (size_t)p * QSZ + d;
#pragma unroll
      for (int mf = 0; mf < 4; ++mf)
#pragma unroll
        for (int r = 0; r < 4; ++r) {
          const int row = r0 + wr + mf * 16 + (lane >> 4) * 4 + r;
          const int b = row >> 10, s = row & 1023;
          float v = acc[mf][nf][r];
          if (p < 2) v = elu1(v);
          dst[((size_t)(hh * B + b) * S + s) * D] = v;
        }
    } else {
#pragma unroll
      for (int mf = 0; mf < 4; ++mf)
#pragma unroll
        for (int r = 0; r < 4; ++r) {
          const int row = r0 + wr + mf * 16 + (lane >> 4) * 4 + r;
          out[(size_t)row * M + col] = acc[mf][nf][r];
        }
    }
  }
}

// ---------------------------------------------------------------------------
// Per-chunk Gram state G_c = sum_t k_t (x) v_t  [64x64] and per-chunk ksum.
// grid = 512 blocks, 256 threads. (unchanged fp32)
// ---------------------------------------------------------------------------
__global__ __launch_bounds__(256) void chunkstate_kernel(
    const float* __restrict__ kws, const float* __restrict__ vws,
    float* __restrict__ G, float* __restrict__ Ks) {
  __shared__ alignas(16) float kT[4096], vT[4096];
  const int tid = threadIdx.x;
  const int bx = blockIdx.x;
  const int hb = bx >> 4, cc = bx & 15;
  const float* kp = kws + (size_t)(hb * S + cc * CH) * D;
  const float* vp = vws + (size_t)(hb * S + cc * CH) * D;
  for (int i = tid; i < 1024; i += 256) {
    reinterpret_cast<float4*>(kT)[i] = reinterpret_cast<const float4*>(kp)[i];
    reinterpret_cast<float4*>(vT)[i] = reinterpret_cast<const float4*>(vp)[i];
  }
  __syncthreads();

  const int e = tid & 63, dg = tid >> 6, d0 = dg * 16;
  float g[16];
#pragma unroll
  for (int j = 0; j < 16; ++j) g[j] = 0.f;

  for (int t = 0; t < CH; ++t) {
    const float vv = vT[t * 64 + e];
#pragma unroll
    for (int jj = 0; jj < 4; ++jj) {
      const float4 kk = reinterpret_cast<const float4*>(kT)[t * 16 + (d0 >> 2) + jj];
      g[jj * 4 + 0] += kk.x * vv;
      g[jj * 4 + 1] += kk.y * vv;
      g[jj * 4 + 2] += kk.z * vv;
      g[jj * 4 + 3] += kk.w * vv;
    }
  }
  float* Gp = G + (size_t)bx * 4096;
#pragma unroll
  for (int j = 0; j < 16; ++j) Gp[(d0 + j) * 64 + e] = g[j];
  if (dg == 0) {
    float ks = 0.f;
    for (int t = 0; t < CH; ++t) ks += kT[t * 64 + e];
    Ks[bx * 64 + e] = ks;
  }
}

// ---------------------------------------------------------------------------
// Exclusive prefix over chunks, one chain per thread.
// grid (32 hb, 16 qd), 256 threads: thread handles (d = qd*4 + tid>>6, e).
// ---------------------------------------------------------------------------
__global__ __launch_bounds__(256) void prefix_kernel(float* __restrict__ G,
                                                     float* __restrict__ Ks) {
  const int hb = blockIdx.x, qd = blockIdx.y;
  const int tid = threadIdx.x;
  const int d = qd * 4 + (tid >> 6), e = tid & 63;
  float* base = G + (size_t)hb * NC * 4096 + d * 64 + e;
  float v[16];
#pragma unroll
  for (int c = 0; c < 16; ++c) v[c] = base[c * 4096];
  float acc = 0.f;
#pragma unroll
  for (int c = 0; c < 16; ++c) { base[c * 4096] = acc; acc += v[c]; }
  if (qd == 0 && tid < 64) {
    float* kb = Ks + hb * (NC * 64) + tid;
    float kv[16];
#pragma unroll
    for (int c = 0; c < 16; ++c) kv[c] = kb[c * 64];
    float ka = 0.f;
#pragma unroll
    for (int c = 0; c < 16; ++c) { kb[c * 64] = ka; ka += kv[c]; }
  }
}

// ---------------------------------------------------------------------------
// Chunk recurrence: one wave per chunk, full 64x64 state in registers.
// lane e owns column e of S. No barriers in the t-loop.
// Writes att[b][s][h*64+e] in bf16 for the output GEMM.
// ---------------------------------------------------------------------------
__global__ __launch_bounds__(64) void chunkout_kernel(
    const float* __restrict__ q, const float* __restrict__ k,
    const float* __restrict__ v, const float* __restrict__ G,
    const float* __restrict__ Ks, u16* __restrict__ att) {
  __shared__ alignas(16) float qT[4096], kT[4096], vT[4096];
  const int tid = threadIdx.x;   // lane = e
  const int bx = blockIdx.x;
  const int hb = bx >> 4, cc = bx & 15;
  const int h = hb >> 2, b = hb & 3;
  const int s0 = cc * CH;
  const float4* qp = reinterpret_cast<const float4*>(q + (size_t)(hb * S + s0) * D);
  const float4* kp = reinterpret_cast<const float4*>(k + (size_t)(hb * S + s0) * D);
  const float4* vp = reinterpret_cast<const float4*>(v + (size_t)(hb * S + s0) * D);
  for (int i = tid; i < 1024; i += 64) {
    reinterpret_cast<float4*>(qT)[i] = qp[i];
    reinterpret_cast<float4*>(kT)[i] = kp[i];
    reinterpret_cast<float4*>(vT)[i] = vp[i];
  }
  __syncthreads();

  float Sacc[64];
#pragma unroll
  for (int d = 0; d < 64; ++d) Sacc[d] = G[(size_t)bx * 4096 + d * 64 + tid];
  float kce = Ks[bx * 64 + tid];

  u16* ap = att + ((size_t)(b * S + s0) * M) + h * D + tid;
  for (int t = 0; t < CH; ++t) {
    const float vv = vT[t * 64 + tid];
    kce += kT[t * 64 + tid];
    float zp = qT[t * 64 + tid] * kce;
#pragma unroll
    for (int off = 32; off; off >>= 1) zp += __shfl_xor(zp, off);
    float p = 0.f;
#pragma unroll
    for (int d4 = 0; d4 < 16; ++d4) {
      const float4 kk = reinterpret_cast<const float4*>(kT)[t * 16 + d4];
      const float4 qq = reinterpret_cast<const float4*>(qT)[t * 16 + d4];
      Sacc[4 * d4 + 0] += kk.x * vv; p += qq.x * Sacc[4 * d4 + 0];
      Sacc[4 * d4 + 1] += kk.y * vv; p += qq.y * Sacc[4 * d4 + 1];
      Sacc[4 * d4 + 2] += kk.z * vv; p += qq.z * Sacc[4 * d4 + 2];
      Sacc[4 * d4 + 3] += kk.w * vv; p += qq.w * Sacc[4 * d4 + 3];
    }
    ap[t * M] = f2bf(p / zp);
  }
}

}  // namespace

extern "C" void kernel_launch(void* const* d_in, const int* in_sizes, int n_in,
                              void* d_out, int out_size, void* d_ws,
                              size_t ws_size, hipStream_t stream) {
  const float* X  = (const float*)d_in[0];
  const float* Wq = (const float*)d_in[2];
  const float* Wk = (const float*)d_in[3];
  const float* Wv = (const float*)d_in[4];
  const float* Wo = (const float*)d_in[5];
  float* out = (float*)d_out;

  float* ws  = (float*)d_ws;
  float* qkv = ws;                               // 3*QSZ fp32
  float* G   = ws + 3 * (size_t)QSZ;             // QSZ fp32
  float* Ks  = ws + 4 * (size_t)QSZ;             // 32768 fp32
  u16*  Xb   = (u16*)(ws + 4 * (size_t)QSZ + 32768);   // 2M bf16
  u16*  att  = Xb;                               // aliased: att written after Xb consumed
  u16*  WCT  = Xb + QSZ;                         // 1536*512 bf16
  u16*  WoT  = WCT + NQKV * M;                   // 512*512 bf16

  convert_x<<<dim3(QSZ / 1024), 256, 0, stream>>>(X, Xb);
  build_wqkv<<<dim3(8, 24), 256, 0, stream>>>(Wq, Wk, Wv, WCT);
  build_wo<<<dim3(8, 8), 256, 0, stream>>>(Wo, WoT);
  gemm_bf16<0><<<dim3(BS / 128, NQKV / 128), 256, 0, stream>>>(Xb, WCT, qkv);
  chunkstate_kernel<<<dim3(H * B * NC), 256, 0, stream>>>(qkv + QSZ,
                                                          qkv + 2 * (size_t)QSZ,
                                                          G, Ks);
  prefix_kernel<<<dim3(H * B, 16), 256, 0, stream>>>(G, Ks);
  chunkout_kernel<<<dim3(H * B * NC), 64, 0, stream>>>(
      qkv, qkv + QSZ, qkv + 2 * (size_t)QSZ, G, Ks, att);
  gemm_bf16<1><<<dim3(BS / 128, M / 128), 256, 0, stream>>>(att, WoT, out);
}

// Round 4
// 60.582 us; speedup vs baseline: 4.3639x; 1.6408x over previous
//
#include <hip/hip_runtime.h>
#include <math.h>

namespace {
typedef unsigned short u16;
typedef __attribute__((ext_vector_type(8))) short bf16x8;
typedef __attribute__((ext_vector_type(4))) float f32x4;

constexpr int H  = 8;
constexpr int B  = 4;
constexpr int S  = 1024;
constexpr int M  = 512;
constexpr int D  = 64;
constexpr int BS = B * S;            // 4096 rows
constexpr int NC = 16;               // chunks per sequence
constexpr int CH = 64;               // chunk length
constexpr int QSZ = H * B * S * D;   // 2097152
constexpr int NQKV = 3 * M;          // 1536

__device__ __forceinline__ float elu1(float x) {
  return x > 0.f ? x + 1.f : __expf(x);
}

__device__ __forceinline__ u16 f2bf(float f) {
  unsigned u = __builtin_bit_cast(unsigned, f);
  u += 0x7fffu + ((u >> 16) & 1u);   // RNE
  return (u16)(u >> 16);
}

__device__ __forceinline__ float bf2f(u16 v) {
  return __builtin_bit_cast(float, ((unsigned)v) << 16);
}

__device__ __forceinline__ void gload16(const u16* g, u16* l) {
  __builtin_amdgcn_global_load_lds(
      (const __attribute__((address_space(1))) unsigned int*)g,
      (__attribute__((address_space(3))) unsigned int*)l, 16, 0, 0);
}

// ---------------------------------------------------------------------------
// X [4096,512] fp32 -> bf16
// ---------------------------------------------------------------------------
__global__ __launch_bounds__(256) void convert_x(const float* __restrict__ X,
                                                 u16* __restrict__ Xb) {
  const int i = blockIdx.x * 256 + threadIdx.x;
  const float4 v = reinterpret_cast<const float4*>(X)[i];
  u16 o[4] = {f2bf(v.x), f2bf(v.y), f2bf(v.z), f2bf(v.w)};
  *reinterpret_cast<uint2*>(Xb + i * 4) = *reinterpret_cast<uint2*>(o);
}

// ---------------------------------------------------------------------------
// WCT[1536][512] bf16 (row = p*512+h*64+d, k-contiguous)
// ---------------------------------------------------------------------------
__global__ __launch_bounds__(256) void build_wqkv(
    const float* __restrict__ Wq, const float* __restrict__ Wk,
    const float* __restrict__ Wv, u16* __restrict__ WCT) {
  __shared__ float t[64][65];
  const int p = blockIdx.y >> 3, h = blockIdx.y & 7;
  const float* W = ((p == 0) ? Wq : (p == 1) ? Wk : Wv) + h * (M * D);
  const int m0 = blockIdx.x * 64;
#pragma unroll
  for (int j = 0; j < 4; ++j) {
    const int i = j * 256 + threadIdx.x;
    const int mm = i >> 4, dd = (i & 15) * 4;
    const float4 v = *reinterpret_cast<const float4*>(W + (m0 + mm) * D + dd);
    t[mm][dd + 0] = v.x; t[mm][dd + 1] = v.y;
    t[mm][dd + 2] = v.z; t[mm][dd + 3] = v.w;
  }
  __syncthreads();
  const int dd = threadIdx.x >> 2, qr = (threadIdx.x & 3) * 16;
  u16* o = WCT + (p * M + h * D + dd) * M + m0 + qr;
#pragma unroll
  for (int i = 0; i < 16; ++i) o[i] = f2bf(t[qr + i][dd]);
}

__global__ __launch_bounds__(256) void build_wo(const float* __restrict__ Wo,
                                                u16* __restrict__ WoT) {
  __shared__ float t[64][65];
  const int m0 = blockIdx.x * 64, n0 = blockIdx.y * 64;
#pragma unroll
  for (int j = 0; j < 4; ++j) {
    const int i = j * 256 + threadIdx.x;
    const int mm = i >> 4, nn = (i & 15) * 4;
    const float4 v = *reinterpret_cast<const float4*>(Wo + (m0 + mm) * M + n0 + nn);
    t[mm][nn + 0] = v.x; t[mm][nn + 1] = v.y;
    t[mm][nn + 2] = v.z; t[mm][nn + 3] = v.w;
  }
  __syncthreads();
  const int nn = threadIdx.x >> 2, qr = (threadIdx.x & 3) * 16;
  u16* o = WoT + (n0 + nn) * M + m0 + qr;
#pragma unroll
  for (int i = 0; i < 16; ++i) o[i] = f2bf(t[qr + i][nn]);
}

// ---------------------------------------------------------------------------
// QKV GEMM: A=Xb[4096][512], BT=WCT[1536][512]. Epilogue scatters bf16:
//   q_b [hb][s][d], k_b [hb][s][d], kT_b [hb][d][s], vT_b [hb][e][s]
// ---------------------------------------------------------------------------
__global__ __launch_bounds__(256) void gemm_qkv(const u16* __restrict__ A,
                                                const u16* __restrict__ BT,
                                                u16* __restrict__ qb,
                                                u16* __restrict__ kb,
                                                u16* __restrict__ kTb,
                                                u16* __restrict__ vTb) {
  __shared__ alignas(16) u16 As[128 * 32];
  __shared__ alignas(16) u16 Bs[128 * 32];
  const int tid = threadIdx.x;
  const int wave = tid >> 6, lane = tid & 63;
  const int r0 = blockIdx.x * 128, c0 = blockIdx.y * 128;
  const int wr = (wave >> 1) * 64, wc = (wave & 1) * 64;

  f32x4 acc[4][4] = {};
  const int lrow = tid >> 2;
  const int lk = (tid & 3) * 8;
  const u16* ga0 = A + (size_t)(r0 + lrow) * 512 + lk;
  const u16* ga1 = A + (size_t)(r0 + 64 + lrow) * 512 + lk;
  const u16* gb0 = BT + (size_t)(c0 + lrow) * 512 + lk;
  const u16* gb1 = BT + (size_t)(c0 + 64 + lrow) * 512 + lk;
  u16* lA0 = &As[wave * 512];
  u16* lA1 = &As[2048 + wave * 512];
  u16* lB0 = &Bs[wave * 512];
  u16* lB1 = &Bs[2048 + wave * 512];

  for (int kt = 0; kt < 16; ++kt) {
    __syncthreads();
    const int ko = kt * 32;
    gload16(ga0 + ko, lA0);
    gload16(ga1 + ko, lA1);
    gload16(gb0 + ko, lB0);
    gload16(gb1 + ko, lB1);
    __syncthreads();
    const bf16x8* As8 = reinterpret_cast<const bf16x8*>(As);
    const bf16x8* Bs8 = reinterpret_cast<const bf16x8*>(Bs);
    bf16x8 af[4], bff[4];
#pragma unroll
    for (int mf = 0; mf < 4; ++mf)
      af[mf] = As8[(wr + mf * 16 + (lane & 15)) * 4 + (lane >> 4)];
#pragma unroll
    for (int nf = 0; nf < 4; ++nf)
      bff[nf] = Bs8[(wc + nf * 16 + (lane & 15)) * 4 + (lane >> 4)];
#pragma unroll
    for (int mf = 0; mf < 4; ++mf)
#pragma unroll
      for (int nf = 0; nf < 4; ++nf)
        acc[mf][nf] = __builtin_amdgcn_mfma_f32_16x16x32_bf16(
            af[mf], bff[nf], acc[mf][nf], 0, 0, 0);
  }

#pragma unroll
  for (int nf = 0; nf < 4; ++nf) {
    const int col = c0 + wc + nf * 16 + (lane & 15);
    const int p = col >> 9, hh = (col >> 6) & 7, dd = col & 63;
#pragma unroll
    for (int mf = 0; mf < 4; ++mf) {
      const int rowb = r0 + wr + mf * 16 + (lane >> 4) * 4;
      const int b = rowb >> 10, s = rowb & 1023;
      const int hb = hh * B + b;
      u16 ov[4];
#pragma unroll
      for (int r = 0; r < 4; ++r) {
        float v = acc[mf][nf][r];
        if (p < 2) v = elu1(v);
        ov[r] = f2bf(v);
      }
      if (p == 0) {
#pragma unroll
        for (int r = 0; r < 4; ++r)
          qb[((size_t)(hb << 10) + s + r) * 64 + dd] = ov[r];
      } else if (p == 1) {
#pragma unroll
        for (int r = 0; r < 4; ++r)
          kb[((size_t)(hb << 10) + s + r) * 64 + dd] = ov[r];
        *reinterpret_cast<uint2*>(kTb + ((size_t)(hb * 64 + dd) << 10) + s) =
            *reinterpret_cast<uint2*>(ov);
      } else {
        *reinterpret_cast<uint2*>(vTb + ((size_t)(hb * 64 + dd) << 10) + s) =
            *reinterpret_cast<uint2*>(ov);
      }
    }
  }
}

// ---------------------------------------------------------------------------
// Output GEMM: att[4096][512] bf16 x WoT -> out fp32
// ---------------------------------------------------------------------------
__global__ __launch_bounds__(256) void gemm_out(const u16* __restrict__ A,
                                                const u16* __restrict__ BT,
                                                float* __restrict__ out) {
  __shared__ alignas(16) u16 As[128 * 32];
  __shared__ alignas(16) u16 Bs[128 * 32];
  const int tid = threadIdx.x;
  const int wave = tid >> 6, lane = tid & 63;
  const int r0 = blockIdx.x * 128, c0 = blockIdx.y * 128;
  const int wr = (wave >> 1) * 64, wc = (wave & 1) * 64;

  f32x4 acc[4][4] = {};
  const int lrow = tid >> 2;
  const int lk = (tid & 3) * 8;
  const u16* ga0 = A + (size_t)(r0 + lrow) * 512 + lk;
  const u16* ga1 = A + (size_t)(r0 + 64 + lrow) * 512 + lk;
  const u16* gb0 = BT + (size_t)(c0 + lrow) * 512 + lk;
  const u16* gb1 = BT + (size_t)(c0 + 64 + lrow) * 512 + lk;
  u16* lA0 = &As[wave * 512];
  u16* lA1 = &As[2048 + wave * 512];
  u16* lB0 = &Bs[wave * 512];
  u16* lB1 = &Bs[2048 + wave * 512];

  for (int kt = 0; kt < 16; ++kt) {
    __syncthreads();
    const int ko = kt * 32;
    gload16(ga0 + ko, lA0);
    gload16(ga1 + ko, lA1);
    gload16(gb0 + ko, lB0);
    gload16(gb1 + ko, lB1);
    __syncthreads();
    const bf16x8* As8 = reinterpret_cast<const bf16x8*>(As);
    const bf16x8* Bs8 = reinterpret_cast<const bf16x8*>(Bs);
    bf16x8 af[4], bff[4];
#pragma unroll
    for (int mf = 0; mf < 4; ++mf)
      af[mf] = As8[(wr + mf * 16 + (lane & 15)) * 4 + (lane >> 4)];
#pragma unroll
    for (int nf = 0; nf < 4; ++nf)
      bff[nf] = Bs8[(wc + nf * 16 + (lane & 15)) * 4 + (lane >> 4)];
#pragma unroll
    for (int mf = 0; mf < 4; ++mf)
#pragma unroll
      for (int nf = 0; nf < 4; ++nf)
        acc[mf][nf] = __builtin_amdgcn_mfma_f32_16x16x32_bf16(
            af[mf], bff[nf], acc[mf][nf], 0, 0, 0);
  }
#pragma unroll
  for (int nf = 0; nf < 4; ++nf) {
    const int col = c0 + wc + nf * 16 + (lane & 15);
#pragma unroll
    for (int mf = 0; mf < 4; ++mf)
#pragma unroll
      for (int r = 0; r < 4; ++r) {
        const int row = r0 + wr + mf * 16 + (lane >> 4) * 4 + r;
        out[(size_t)row * M + col] = acc[mf][nf][r];
      }
  }
}

// ---------------------------------------------------------------------------
// Chunk Gram state via MFMA: G^T = V^T · K  (rows e, cols d), fp32 out.
// Also per-chunk k column sums. One block (4 waves) per chunk.
// ---------------------------------------------------------------------------
__global__ __launch_bounds__(256) void chunkstate_mfma(
    const u16* __restrict__ kTb, const u16* __restrict__ vTb,
    float* __restrict__ G32, float* __restrict__ Ks) {
  const int tid = threadIdx.x, wave = tid >> 6, lane = tid & 63;
  const int bx = blockIdx.x, hb = bx >> 4, cc = bx & 15, s0 = cc * CH;
  const u16* vbase = vTb + ((size_t)hb * 64) * 1024 + s0;
  const u16* kbase = kTb + ((size_t)hb * 64) * 1024 + s0;

  bf16x8 av[2];
#pragma unroll
  for (int ks = 0; ks < 2; ++ks)
    av[ks] = *reinterpret_cast<const bf16x8*>(
        vbase + (size_t)(wave * 16 + (lane & 15)) * 1024 + ks * 32 + (lane >> 4) * 8);

  f32x4 acc[4] = {};
#pragma unroll
  for (int fd = 0; fd < 4; ++fd)
#pragma unroll
    for (int ks = 0; ks < 2; ++ks) {
      bf16x8 bk = *reinterpret_cast<const bf16x8*>(
          kbase + (size_t)(fd * 16 + (lane & 15)) * 1024 + ks * 32 + (lane >> 4) * 8);
      acc[fd] = __builtin_amdgcn_mfma_f32_16x16x32_bf16(av[ks], bk, acc[fd], 0, 0, 0);
    }

  float* Gp = G32 + (size_t)bx * 4096;
#pragma unroll
  for (int fd = 0; fd < 4; ++fd)
#pragma unroll
    for (int r = 0; r < 4; ++r) {
      const int e = wave * 16 + (lane >> 4) * 4 + r;
      const int d = fd * 16 + (lane & 15);
      Gp[e * 64 + d] = acc[fd][r];
    }

  const int d = tid >> 2, tq = tid & 3;
  const u16* kp = kbase + (size_t)d * 1024 + tq * 16;
  float ks = 0.f;
#pragma unroll
  for (int j = 0; j < 16; ++j) ks += bf2f(kp[j]);
  ks += __shfl_xor(ks, 1);
  ks += __shfl_xor(ks, 2);
  if (tq == 0) Ks[bx * 64 + d] = ks;
}

// ---------------------------------------------------------------------------
// Exclusive prefix over chunks; emits bf16 G^T (exclusive) and in-place
// exclusive Ks. grid (32 hb, 16 e-groups), 256 threads.
// ---------------------------------------------------------------------------
__global__ __launch_bounds__(256) void prefix_kernel(
    const float* __restrict__ G32, u16* __restrict__ GTb,
    float* __restrict__ Ks) {
  const int hb = blockIdx.x, eg = blockIdx.y;
  const int tid = threadIdx.x;
  const int e = eg * 4 + (tid >> 6), d = tid & 63;
  const size_t base = ((size_t)(hb * 16) * 64 + e) * 64 + d;
  float acc = 0.f;
#pragma unroll
  for (int c = 0; c < 16; ++c) {
    const float v = G32[base + (size_t)c * 4096];
    GTb[base + (size_t)c * 4096] = f2bf(acc);
    acc += v;
  }
  if (eg == 0 && tid < 64) {
    float ka = 0.f;
#pragma unroll
    for (int c = 0; c < 16; ++c) {
      const int idx = (hb * 16 + c) * 64 + tid;
      const float v = Ks[idx];
      Ks[idx] = ka;
      ka += v;
    }
  }
}

// ---------------------------------------------------------------------------
// Chunk output via MFMA:  O = Q·G_prev + tril(Q K^T)·V ;  Z = Q·kc + rowsum.
// One block (4 waves) per chunk; wave w owns rows i0=w*16..+15.
// ---------------------------------------------------------------------------
__global__ __launch_bounds__(256) void chunkout_mfma(
    const u16* __restrict__ qb, const u16* __restrict__ kb,
    const u16* __restrict__ vTb, const u16* __restrict__ GTb,
    const float* __restrict__ Kc, u16* __restrict__ att) {
  __shared__ alignas(16) u16 Qs[4096], Kls[4096], Vs[4096], Gs[4096], Astg[4096];
  const int tid = threadIdx.x, wave = tid >> 6, lane = tid & 63;
  const int bx = blockIdx.x, hb = bx >> 4, cc = bx & 15, s0 = cc * CH;
  const int h = hb >> 2, b = hb & 3;

  // stage Q, K, G (each 4096 u16 = 8 segments of 64 lanes x 8 u16), V rows
  {
    const u16* qg = qb + ((size_t)(hb << 10) + s0) * 64;
    const u16* kg = kb + ((size_t)(hb << 10) + s0) * 64;
    const u16* gg = GTb + (size_t)bx * 4096;
#pragma unroll
    for (int j = 0; j < 2; ++j) {               // FIX: was j<4 (LDS overrun)
      const int off = j * 2048 + wave * 512;
      gload16(qg + off + lane * 8, Qs + off);
      gload16(kg + off + lane * 8, Kls + off);
      gload16(gg + off + lane * 8, Gs + off);
    }
    const u16* vg = vTb + ((size_t)hb * 64) * 1024 + s0;
#pragma unroll
    for (int j = 0; j < 2; ++j) {
      const int e0 = j * 32 + wave * 8;
      gload16(vg + (size_t)(e0 + (lane >> 3)) * 1024 + (lane & 7) * 8,
              Vs + e0 * 64);
    }
  }
  __syncthreads();

  const bf16x8* Qs8 = reinterpret_cast<const bf16x8*>(Qs);
  const bf16x8* Ks8 = reinterpret_cast<const bf16x8*>(Kls);
  const bf16x8* Vs8 = reinterpret_cast<const bf16x8*>(Vs);
  const bf16x8* Gs8 = reinterpret_cast<const bf16x8*>(Gs);
  const bf16x8* As8 = reinterpret_cast<const bf16x8*>(Astg);

  const int i0 = wave * 16;
  const int l15 = lane & 15, lk = lane >> 4;

  bf16x8 aq[2];
#pragma unroll
  for (int ks = 0; ks < 2; ++ks)
    aq[ks] = Qs8[(i0 + l15) * 8 + ks * 4 + lk];

  // A = Q K^T
  f32x4 a[4] = {};
#pragma unroll
  for (int fj = 0; fj < 4; ++fj)
#pragma unroll
    for (int ks = 0; ks < 2; ++ks) {
      bf16x8 bk = Ks8[(fj * 16 + l15) * 8 + ks * 4 + lk];
      a[fj] = __builtin_amdgcn_mfma_f32_16x16x32_bf16(aq[ks], bk, a[fj], 0, 0, 0);
    }

  // mask, rowsum, Z
  const float4 kc4 = *reinterpret_cast<const float4*>(Kc + bx * 64 + l15 * 4);
  float z[4];
  const int rbase = lk * 4;
#pragma unroll
  for (int r = 0; r < 4; ++r) {
    const int il = rbase + r;
    float sum = 0.f;
#pragma unroll
    for (int fj = 0; fj < 4; ++fj) {
      const int j = fj * 16 + l15;
      if (j > i0 + il) a[fj][r] = 0.f;
      sum += a[fj][r];
    }
    const uint2 qrow = *reinterpret_cast<const uint2*>(Qs + (i0 + il) * 64 + l15 * 4);
    const u16* qr16 = reinterpret_cast<const u16*>(&qrow);
    sum += bf2f(qr16[0]) * kc4.x + bf2f(qr16[1]) * kc4.y +
           bf2f(qr16[2]) * kc4.z + bf2f(qr16[3]) * kc4.w;
    z[r] = sum;
  }
#pragma unroll
  for (int off = 1; off <= 8; off <<= 1)
#pragma unroll
    for (int r = 0; r < 4; ++r) z[r] += __shfl_xor(z[r], off);

  // stash masked A as bf16
#pragma unroll
  for (int fj = 0; fj < 4; ++fj)
#pragma unroll
    for (int r = 0; r < 4; ++r)
      Astg[(i0 + rbase + r) * 64 + fj * 16 + l15] = f2bf(a[fj][r]);
  __syncthreads();

  // O = Q·G + Amask·V
  f32x4 o[4] = {};
#pragma unroll
  for (int fe = 0; fe < 4; ++fe) {
#pragma unroll
    for (int ks = 0; ks < 2; ++ks) {
      bf16x8 bg = Gs8[(fe * 16 + l15) * 8 + ks * 4 + lk];
      o[fe] = __builtin_amdgcn_mfma_f32_16x16x32_bf16(aq[ks], bg, o[fe], 0, 0, 0);
    }
#pragma unroll
    for (int ks = 0; ks < 2; ++ks) {
      bf16x8 aa = As8[(i0 + l15) * 8 + ks * 4 + lk];
      bf16x8 bv = Vs8[(fe * 16 + l15) * 8 + ks * 4 + lk];
      o[fe] = __builtin_amdgcn_mfma_f32_16x16x32_bf16(aa, bv, o[fe], 0, 0, 0);
    }
  }

  float rz[4];
#pragma unroll
  for (int r = 0; r < 4; ++r) rz[r] = 1.f / z[r];
#pragma unroll
  for (int fe = 0; fe < 4; ++fe)
#pragma unroll
    for (int r = 0; r < 4; ++r) {
      const int srow = s0 + i0 + rbase + r;
      att[((size_t)(b << 10) + srow) * 512 + h * 64 + fe * 16 + l15] =
          f2bf(o[fe][r] * rz[r]);
    }
}

}  // namespace

extern "C" void kernel_launch(void* const* d_in, const int* in_sizes, int n_in,
                              void* d_out, int out_size, void* d_ws,
                              size_t ws_size, hipStream_t stream) {
  const float* X  = (const float*)d_in[0];
  const float* Wq = (const float*)d_in[2];
  const float* Wk = (const float*)d_in[3];
  const float* Wv = (const float*)d_in[4];
  const float* Wo = (const float*)d_in[5];
  float* out = (float*)d_out;

  u16* Xb  = (u16*)d_ws;            // 2M u16
  u16* att = Xb;                    // alias: written after Xb fully consumed
  u16* WCT = Xb + QSZ;              // 1536*512
  u16* WoT = WCT + NQKV * M;        // 512*512
  u16* qb  = WoT + M * M;           // 2M each
  u16* kb  = qb + QSZ;
  u16* kTb = kb + QSZ;
  u16* vTb = kTb + QSZ;
  u16* GTb = vTb + QSZ;
  float* G32 = (float*)(GTb + QSZ); // 2M fp32
  float* Ks  = G32 + QSZ;           // 32768 fp32

  convert_x<<<dim3(QSZ / 1024), 256, 0, stream>>>(X, Xb);
  build_wqkv<<<dim3(8, 24), 256, 0, stream>>>(Wq, Wk, Wv, WCT);
  build_wo<<<dim3(8, 8), 256, 0, stream>>>(Wo, WoT);
  gemm_qkv<<<dim3(BS / 128, NQKV / 128), 256, 0, stream>>>(Xb, WCT, qb, kb,
                                                           kTb, vTb);
  chunkstate_mfma<<<dim3(H * B * NC), 256, 0, stream>>>(kTb, vTb, G32, Ks);
  prefix_kernel<<<dim3(H * B, 16), 256, 0, stream>>>(G32, GTb, Ks);
  chunkout_mfma<<<dim3(H * B * NC), 256, 0, stream>>>(qb, kb, vTb, GTb, Ks,
                                                      att);
  gemm_out<<<dim3(BS / 128, M / 128), 256, 0, stream>>>(att, WoT, out);
}